// Round 3
// baseline (116.290 us; speedup 1.0000x reference)
//
#include <hip/hip_runtime.h>

#define N2 128
#define MM 16384
#define START 6
#define TC 16        // columns per block -> 1024 blocks -> 4 blocks/CU
#define BT 256       // 4 waves; 16 virtual workers (vw) of 16 lanes
#define PST 17       // padded LDS stride: <=2-way bank conflicts (free)

// conv of one 8-row chunk, split by role: odd lane-group does scalar prologue
// [J..jend] + octets down to Jmid; even does octets [0, Jmid). Ring f-window.
__device__ __forceinline__ void conv_chunk(int i0, int odd, int c,
                                           const float* __restrict__ predT,
                                           const float* __restrict__ fT,
                                           float acc[8]) {
#pragma unroll
    for (int k = 0; k < 8; ++k) acc[k] = 0.f;
    const int J = (i0 - 1) & ~7;
    const int Jmid = (J >> 1) & ~7;
    int jtop, jbot;
    if (odd) {
        const int jend = (i0 + 5 < 125) ? (i0 + 5) : 125;
        for (int j = J; j <= jend; ++j) {
            float pv = predT[j * PST + c];
#pragma unroll
            for (int k = 0; k < 8; ++k) {
                int d = i0 + k - j;
                if (d >= 2 && (i0 + k) < N2)
                    acc[k] += pv * fT[d * PST + c];
            }
        }
        jtop = J;  jbot = Jmid;        // octets [Jmid, J)
    } else {
        jtop = Jmid; jbot = 0;         // octets [0, Jmid)
    }
    if (jtop > jbot) {
        float c8[8];
        const int d0f = i0 - jtop + 1;  // >= 2, <= 78 in all cases
#pragma unroll
        for (int k = 0; k < 8; ++k) c8[k] = fT[(d0f + k) * PST + c];
        for (int j8 = jtop - 8; j8 >= jbot; j8 -= 8) {
            const int dbase = i0 - j8 - 7;
#pragma unroll
            for (int s = 0; s < 8; ++s) {
                float pv = predT[(j8 + 7 - s) * PST + c];
#pragma unroll
                for (int k = 0; k < 8; ++k)
                    acc[k] += pv * c8[(s + k) & 7];
                int dr = dbase + s + 8;
                if (dr > N2 - 1) dr = N2 - 1;  // clamped slots only feed rows >= N2 (discarded)
                c8[s] = fT[dr * PST + c];
            }
        }
    }
}

__global__ __launch_bounds__(BT, 4) void npi_fused(
    const float* __restrict__ rt, const float* __restrict__ dgt,
    const float* __restrict__ si, const float* __restrict__ f,
    const float* __restrict__ seed, float* __restrict__ out)
{
    __shared__ float predT[N2 * PST];     // [time][col] stride 17, 8.5 KiB
    __shared__ float fT[N2 * PST];        // staged f, 8.5 KiB
    __shared__ float red[7 * 16 * PST];   // phase-1 H partials, 7.4 KiB
    __shared__ float si_s[N2];
    __shared__ float lred[4];

    const int t = threadIdx.x;
    const int c = t & 15;          // column within block
    const int vw = t >> 4;         // virtual worker 0..15 (16-lane group)
    const int m = blockIdx.x * TC + c;

    // ---- stage f -> fT (latency overlapped with all of phase 1), si, seeds ----
#pragma unroll
    for (int q = 0; q < 8; ++q) {
        int d = (q << 4) + vw;
        fT[d * PST + c] = f[d * MM + m];
    }
    if (t < N2) si_s[t] = si[t];
    if (vw < START) predT[vw * PST + c] = seed[vw * MM + m];
    else if (vw < 16) red[vw * PST + c] = rt[vw * MM + m];  // rt rows 6..15 for step-0
    __syncthreads();

    float sr[16];
#pragma unroll
    for (int k = 1; k < 16; ++k) sr[k] = si_s[k];

    // ---- phase 1, chunk 0: seeds + triangle (vw 15) ----
    if (vw == 15) {
        float v[16];
#pragma unroll
        for (int k = 0; k < 16; ++k) {
            if (k < START) {
                v[k] = predT[k * PST + c];
            } else {
                float s = 0.f;
#pragma unroll
                for (int kk = 0; kk < 16; ++kk)
                    if (kk < k) s += v[kk] * sr[k - kk];
                v[k] = red[k * PST + c] * s;
                predT[k * PST + c] = v[k];
            }
        }
    }
    __syncthreads();

    // ---- phase 1, chunks b = 1..7 ----
    for (int b = 1; b < 8; ++b) {
        const int i0 = b << 4;
        float r16[16];
        if (vw == 15) {
#pragma unroll
            for (int k = 0; k < 16; ++k) r16[k] = rt[(i0 + k) * MM + m];
        } else if (vw < b) {
            const int j0 = vw << 4;
            const int D0 = i0 - j0 - 15;   // >= 1
            float c16[16];
#pragma unroll
            for (int e = 0; e < 16; ++e) c16[(e + 1) & 15] = si_s[D0 + e];
            float acc[16];
#pragma unroll
            for (int k = 0; k < 16; ++k) acc[k] = 0.f;
#pragma unroll
            for (int s = 0; s < 16; ++s) {
                float p = predT[(j0 + 15 - s) * PST + c];
#pragma unroll
                for (int k = 0; k < 16; ++k)
                    acc[k] += p * c16[(s + k + 1) & 15];
                if (s < 15) c16[(s + 1) & 15] = si_s[D0 + 16 + s];
            }
#pragma unroll
            for (int k = 0; k < 16; ++k)
                red[((vw << 4) + k) * PST + c] = acc[k];
        }
        __syncthreads();

        // reduction: exactly one (k, col) element per thread
        {
            float tot = 0.f;
            for (int w2 = 0; w2 < b; ++w2)
                tot += red[((w2 << 4) + vw) * PST + c];
            predT[(i0 + vw) * PST + c] = tot;
        }
        __syncthreads();

        if (vw == 15) {
            float h[16];
#pragma unroll
            for (int k = 0; k < 16; ++k) h[k] = predT[(i0 + k) * PST + c];  // independent loads
            float v[16];
#pragma unroll
            for (int k = 0; k < 16; ++k) {
                float s = h[k];
#pragma unroll
                for (int kk = 0; kk < 16; ++kk)
                    if (kk < k) s += v[kk] * sr[k - kk];
                v[k] = r16[k] * s;
                predT[(i0 + k) * PST + c] = v[k];
            }
        }
        __syncthreads();
    }

    // ---- phase 2: deaths conv + MSE ----
    float lsum = 0.f;
    if (vw >= 8 && vw < 8 + START) {
        int i = vw - 8;
        float di = dgt[i * MM + m];
        float d0 = (i == 0) ? (1e-9f - di) : di;
        lsum = d0 * d0;
    }

    const int p = vw >> 1;
    const int odd = vw & 1;
    const int i0a = START + (p << 3);          // 6..62
    const int i0b = START + ((15 - p) << 3);   // 126..70
    float accA[8], accB[8];
    conv_chunk(i0a, odd, c, predT, fT, accA);
    conv_chunk(i0b, odd, c, predT, fT, accB);

    // combine the two j-halves across the lane pair (lane ^ 16)
#pragma unroll
    for (int k = 0; k < 8; ++k) {
        accA[k] += __shfl_xor(accA[k], 16, 64);
        accB[k] += __shfl_xor(accB[k], 16, 64);
    }
    // even lane-group finalizes chunk A, odd finalizes chunk B
    const int i0o = odd ? i0b : i0a;
#pragma unroll
    for (int k = 0; k < 8; ++k) {
        int i = i0o + k;
        if (i < N2) {
            float av = odd ? accB[k] : accA[k];
            float diff = av - dgt[i * MM + m];
            lsum += diff * diff;
        }
    }

    // ---- loss reduction: wave shuffle -> LDS -> one atomic per block ----
#pragma unroll
    for (int off = 32; off > 0; off >>= 1)
        lsum += __shfl_down(lsum, off, 64);
    if ((t & 63) == 0) lred[t >> 6] = lsum;
    __syncthreads();
    if (t == 0) {
        float tot = lred[0] + lred[1] + lred[2] + lred[3];
        atomicAdd(out, tot * (1.0f / ((float)N2 * (float)MM)));
    }
}

extern "C" void kernel_launch(void* const* d_in, const int* in_sizes, int n_in,
                              void* d_out, int out_size, void* d_ws, size_t ws_size,
                              hipStream_t stream) {
    const float* rt   = (const float*)d_in[0];
    const float* dgt  = (const float*)d_in[1];
    const float* si   = (const float*)d_in[2];
    const float* f    = (const float*)d_in[3];
    const float* seed = (const float*)d_in[4];

    hipMemsetAsync(d_out, 0, sizeof(float), stream);
    npi_fused<<<dim3(MM / TC), dim3(BT), 0, stream>>>(
        rt, dgt, si, f, seed, (float*)d_out);
}

// Round 4
// 105.879 us; speedup vs baseline: 1.0983x; 1.0983x over previous
//
#include <hip/hip_runtime.h>

#define N2 128
#define MM 16384
#define START 6
#define CB 32        // columns per block -> 512 blocks -> 2 blocks/CU
#define BT 256       // 4 waves = 8 half-wave shares (32 lanes each)
#define PROWS 136    // predT rows: 0..127 data, 128..135 zero
#define FROWS 152    // fTd rows: index = 16 + d; zero outside d in [2,127]

__global__ __launch_bounds__(BT, 2) void npi_fused(
    const float* __restrict__ rt, const float* __restrict__ dgt,
    const float* __restrict__ si, const float* __restrict__ f,
    const float* __restrict__ seed, float* __restrict__ out)
{
    __shared__ float predT[PROWS * CB];   // 17.0 KiB  [row][col]
    __shared__ float fTd[FROWS * CB];     // 19.0 KiB  [16+d][col]
    __shared__ float part[4 * 16 * CB];   //  8.0 KiB  [wave][k][col]
    __shared__ float si_s[N2];
    __shared__ float lred[4];

    const int t = threadIdx.x;
    const int c = t & (CB - 1);
    const int w = t >> 6;          // wave 0..3
    const int g = t >> 5;          // half-wave share 0..7
    const int hw = g & 1;          // half within wave
    const int m = blockIdx.x * CB + c;

    // f rows for this share -> registers; loads stream under phase 1,
    // written to LDS only after phase 1 (no stall).
    float fregs[16];
#pragma unroll
    for (int q = 0; q < 16; ++q)
        fregs[q] = f[((g << 4) + q) * MM + m];

    if (t < N2) si_s[t] = si[t];
    if (g < START) predT[(g << 5) + c] = seed[g * MM + m];
    predT[((128 + g) << 5) + c] = 0.f;            // zero pad rows 128..135
    fTd[(g << 5) + c] = 0.f;                      // zero pad idx 0..17
    fTd[((8 + g) << 5) + c] = 0.f;
    if (g < 2) fTd[((16 + g) << 5) + c] = 0.f;
    fTd[((144 + g) << 5) + c] = 0.f;              // zero pad idx 144..151

    float r16v[16];
#pragma unroll
    for (int k = 0; k < 16; ++k)
        r16v[k] = rt[k * MM + m];                 // chunk-0 rows (6..15 used)

    __syncthreads();

    float sr[16];
#pragma unroll
    for (int k = 1; k < 16; ++k) sr[k] = si_s[k];

    // ---- phase 1, chunk 0: triangle from seeds (redundant per wave) ----
    {
        float v[16];
#pragma unroll
        for (int k = 0; k < 16; ++k) {
            if (k < START) {
                v[k] = predT[(k << 5) + c];
            } else {
                float s = 0.f;
#pragma unroll
                for (int kk = 0; kk < 16; ++kk)
                    if (kk < k) s += v[kk] * sr[k - kk];
                v[k] = r16v[k] * s;
            }
        }
        if (w == 3 && hw == 0) {
#pragma unroll
            for (int k = START; k < 16; ++k) predT[(k << 5) + c] = v[k];
        }
    }
    __syncthreads();

    // ---- phase 1, chunks b = 1..7: 8 equal j-shares of 2b each ----
    for (int b = 1; b < 8; ++b) {
        const int i0 = b << 4;
        const int nst = b << 1;                   // steps per share (<= 14)
#pragma unroll
        for (int k = 0; k < 16; ++k)
            r16v[k] = rt[(i0 + k) * MM + m];      // prefetch for triangle

        const int jhi = nst * (g + 1);            // share j in [jhi-nst, jhi)
        const int base = i0 - jhi + 1;            // >= 1
        float c16[16];
#pragma unroll
        for (int e = 0; e < 16; ++e) c16[e] = si_s[base + e];
        float acc[16];
#pragma unroll
        for (int k = 0; k < 16; ++k) acc[k] = 0.f;
#pragma unroll
        for (int u = 0; u < 14; ++u) {            // nst <= 14; uniform guard
            if (u < nst) {
                float p = predT[((jhi - 1 - u) << 5) + c];
#pragma unroll
                for (int k = 0; k < 16; ++k)
                    acc[k] += p * c16[(u + k) & 15];
                if (u + 1 < nst) c16[u] = si_s[base + 16 + u];  // max idx 127
            }
        }
        // fold the two shares of each wave (free, in-register)
#pragma unroll
        for (int k = 0; k < 16; ++k)
            acc[k] += __shfl_xor(acc[k], 32, 64);
        if (hw == 0) {
#pragma unroll
            for (int k = 0; k < 16; ++k)
                part[(((w << 4) + k) << 5) + c] = acc[k];
        }
        __syncthreads();

        // reduce 4 wave-partials + triangle (redundant per wave: all SIMDs busy)
        float v[16];
#pragma unroll
        for (int k = 0; k < 16; ++k) {
            float s = part[(k << 5) + c] + part[((16 + k) << 5) + c]
                    + part[((32 + k) << 5) + c] + part[((48 + k) << 5) + c];
#pragma unroll
            for (int kk = 0; kk < 16; ++kk)
                if (kk < k) s += v[kk] * sr[k - kk];
            v[k] = r16v[k] * s;
        }
        // wave w writes rows [i0+4w, i0+4w+4), 2 rows per half-wave
        {
            float a0, a1;
            if (w == 0)      { a0 = hw ? v[2]  : v[0];  a1 = hw ? v[3]  : v[1];  }
            else if (w == 1) { a0 = hw ? v[6]  : v[4];  a1 = hw ? v[7]  : v[5];  }
            else if (w == 2) { a0 = hw ? v[10] : v[8];  a1 = hw ? v[11] : v[9];  }
            else             { a0 = hw ? v[14] : v[12]; a1 = hw ? v[15] : v[13]; }
            const int r0 = i0 + (w << 2) + (hw << 1);
            predT[(r0 << 5) + c] = a0;
            predT[((r0 + 1) << 5) + c] = a1;
        }
        __syncthreads();
    }

    // ---- stage f -> LDS (loads long since landed) ----
#pragma unroll
    for (int q = 0; q < 16; ++q) {
        int d = (g << 4) + q;
        fTd[((16 + d) << 5) + c] = (d < 2) ? 0.f : fregs[q];
    }
    __syncthreads();

    // ---- phase 2: deaths conv + MSE ----
    float lsum = 0.f;
    if (hw == 0) {
        float dv = dgt[w * MM + m];
        float e0 = (w == 0) ? (1e-9f - dv) : dv;
        lsum += e0 * e0;
        if (w < 2) {
            float d2 = dgt[(4 + w) * MM + m];
            lsum += d2 * d2;
        }
    }

#pragma unroll
    for (int half = 0; half < 2; ++half) {
        const int n = half ? (7 - w) : w;         // pairs {n, 7-n}: balanced
        const int i0 = START + (n << 4);          // 6..118
        const int jhi2 = i0 + 14;                 // even
        const int steps = jhi2 >> 1;              // equal per half (<= 66)
        const int jh = hw ? jhi2 : (jhi2 >> 1);   // this half's j-range top
        const int fb = 17 + i0 - jh;              // ring base index into fTd

        float dg[16];
#pragma unroll
        for (int k = 0; k < 16; ++k)
            dg[k] = (i0 + k < N2) ? dgt[(i0 + k) * MM + m] : 0.f;

        float cf[16];
#pragma unroll
        for (int e = 0; e < 16; ++e) cf[e] = fTd[((fb + e) << 5) + c];
        float acc[16];
#pragma unroll
        for (int k = 0; k < 16; ++k) acc[k] = 0.f;

        for (int sb = 0; sb < steps; sb += 16) {
#pragma unroll
            for (int u = 0; u < 16; ++u) {
                int s = sb + u;
                if (s < steps) {                  // uniform guard
                    float p = predT[((jh - 1 - s) << 5) + c];  // rows<=131, pad=0
#pragma unroll
                    for (int k = 0; k < 16; ++k)
                        acc[k] += p * cf[(u + k) & 15];
                    cf[u] = fTd[((fb + 16 + s) << 5) + c];     // max idx 150
                }
            }
        }
#pragma unroll
        for (int k = 0; k < 16; ++k)
            acc[k] += __shfl_xor(acc[k], 32, 64);
        if (hw == 0) {
#pragma unroll
            for (int k = 0; k < 16; ++k) {
                if (i0 + k < N2) {
                    float diff = acc[k] - dg[k];
                    lsum += diff * diff;
                }
            }
        }
    }

    // ---- loss reduction ----
#pragma unroll
    for (int off = 32; off > 0; off >>= 1)
        lsum += __shfl_down(lsum, off, 64);
    if ((t & 63) == 0) lred[w] = lsum;
    __syncthreads();
    if (t == 0)
        atomicAdd(out, (lred[0] + lred[1] + lred[2] + lred[3]) *
                       (1.0f / ((float)N2 * (float)MM)));
}

extern "C" void kernel_launch(void* const* d_in, const int* in_sizes, int n_in,
                              void* d_out, int out_size, void* d_ws, size_t ws_size,
                              hipStream_t stream) {
    const float* rt   = (const float*)d_in[0];
    const float* dgt  = (const float*)d_in[1];
    const float* si   = (const float*)d_in[2];
    const float* f    = (const float*)d_in[3];
    const float* seed = (const float*)d_in[4];

    hipMemsetAsync(d_out, 0, sizeof(float), stream);
    npi_fused<<<dim3(MM / CB), dim3(BT), 0, stream>>>(
        rt, dgt, si, f, seed, (float*)d_out);
}